// Round 2
// baseline (3098.650 us; speedup 1.0000x reference)
//
#include <hip/hip_runtime.h>

// GraphConv SpMM: out[row[e], :] += edge_vals[e] * x[col[e], :]
// N = 500000, E = 8000000, D = 64, fp32.
//
// Round 6 pipeline (sort-free, MLP-restored reduce):
//   1. bucket histogram (bucket = row>>8, 1954 buckets)
//   2. single-block scan -> bucket run starts
//   3. bin edges into bucket runs (1024-thread blocks, 32K-edge tiles,
//      packs (lrow<<19 | col, val)). Order within bucket is arbitrary.
//   4. reduce_bucket: one block per bucket, 64KB LDS fp32 accumulator
//      acc[256 rows][64 feats]. feat = lane (D == wavefront size):
//      gather is one coalesced 256B load per edge, accumulate is ONE
//      ds_add_f32 per edge hitting banks lane%32 (2 lanes/bank = free).
//      Round-5 failure: compiler serialized the gather (VGPR=8, 3.5%
//      VALU). Fix: explicit 2-stage software pipeline with 8-edge
//      batches (8 loads in flight while previous batch's ds_adds
//      drain) + __hip_atomic_fetch_add WORKGROUP scope -> native
//      ds_add_f32 (plain atomicAdd on shared float risks a CAS loop).

#define D_FEAT 64
#define RPB 256                // rows per bucket
#define BKT_SHIFT 8
#define MAX_BKT 2048
#define TILE_EDGES 8192        // hist tile (256 threads * EPT)
#define EPT 32                 // edges per thread in hist/bin
#define TILE_BIN 32768         // bin tile (1024 threads * EPT)
#define BIN_THREADS 1024
#define BATCH 8                // reduce pipeline depth (edges per batch)

typedef float vf4 __attribute__((ext_vector_type(4)));

// ---------------- bucket histogram ----------------
__global__ __launch_bounds__(256)
void hist_kernel(const int* __restrict__ row, int* __restrict__ cnt_g,
                 int n_edges, int kb) {
    __shared__ int cnt[MAX_BKT];
    for (int i = threadIdx.x; i < kb; i += 256) cnt[i] = 0;
    __syncthreads();
    int base = blockIdx.x * TILE_EDGES;
#pragma unroll
    for (int k = 0; k < EPT; k++) {
        int e = base + k * 256 + threadIdx.x;
        if (e < n_edges) atomicAdd(&cnt[row[e] >> BKT_SHIFT], 1);
    }
    __syncthreads();
    for (int i = threadIdx.x; i < kb; i += 256) {
        int c = cnt[i];
        if (c) atomicAdd(&cnt_g[i], c);
    }
}

// ---------------- single-block scan over kb buckets ----------------
__global__ __launch_bounds__(256)
void scan_kernel(const int* __restrict__ cnt_g, int* __restrict__ start,
                 int* __restrict__ gcursor, int kb) {
    __shared__ int sums[256];
    int vals[8];
    int base = threadIdx.x * 8;
    int s = 0;
#pragma unroll
    for (int i = 0; i < 8; i++) {
        int idx = base + i;
        int v = (idx < kb) ? cnt_g[idx] : 0;
        s += v;
        vals[i] = s;
    }
    sums[threadIdx.x] = s;
    __syncthreads();
    for (int off = 1; off < 256; off <<= 1) {
        int t = (threadIdx.x >= off) ? sums[threadIdx.x - off] : 0;
        __syncthreads();
        sums[threadIdx.x] += t;
        __syncthreads();
    }
    int toff = (threadIdx.x > 0) ? sums[threadIdx.x - 1] : 0;
#pragma unroll
    for (int i = 0; i < 8; i++) {
        int idx = base + i;
        if (idx < kb) {
            int incl = vals[i] + toff;
            int v = vals[i] - (i ? vals[i - 1] : 0);
            start[idx + 1] = incl;
            gcursor[idx] = incl - v;
        }
    }
    if (threadIdx.x == 0) start[0] = 0;
}

// ---------------- bin edges into bucket runs ----------------
__global__ __launch_bounds__(BIN_THREADS)
void bin_kernel(const int* __restrict__ row, const int* __restrict__ col,
                const float* __restrict__ val,
                int* __restrict__ gcursor, int2* __restrict__ packed,
                int n_edges, int kb) {
    __shared__ int cnt[MAX_BKT];
    __shared__ int base_s[MAX_BKT];
    for (int i = threadIdx.x; i < kb; i += BIN_THREADS) cnt[i] = 0;
    __syncthreads();
    int tbase = blockIdx.x * TILE_BIN;
    int r_[EPT];
#pragma unroll
    for (int k = 0; k < EPT; k++) {
        int e = tbase + k * BIN_THREADS + threadIdx.x;
        int r = (e < n_edges) ? row[e] : -1;
        r_[k] = r;
        if (r >= 0) atomicAdd(&cnt[r >> BKT_SHIFT], 1);
    }
    __syncthreads();
    for (int i = threadIdx.x; i < kb; i += BIN_THREADS) {
        int c = cnt[i];
        base_s[i] = c ? atomicAdd(&gcursor[i], c) : 0;
        cnt[i] = 0;
    }
    __syncthreads();
#pragma unroll
    for (int k = 0; k < EPT; k++) {
        int r = r_[k];
        if (r >= 0) {
            int e = tbase + k * BIN_THREADS + threadIdx.x;
            int b = r >> BKT_SHIFT;
            int rank = atomicAdd(&cnt[b], 1);
            packed[base_s[b] + rank] =
                make_int2(((r & (RPB - 1)) << 19) | col[e], __float_as_int(val[e]));
        }
    }
}

// ---------------- fused bucket reduce (LDS fp32 accumulator) ----------------
__device__ __forceinline__ void lds_fadd(float* p, float v) {
    // WORKGROUP-scope relaxed fadd on addrspace(3) f32 -> native ds_add_f32
    __hip_atomic_fetch_add(p, v, __ATOMIC_RELAXED, __HIP_MEMORY_SCOPE_WORKGROUP);
}

__global__ __launch_bounds__(1024)
void reduce_bucket(const float* __restrict__ x, const int2* __restrict__ packed,
                   const int* __restrict__ start, float* __restrict__ out,
                   int n_nodes) {
    __shared__ float acc[RPB * D_FEAT];   // 64 KB: acc[row][feat]
    const int tid = threadIdx.x;

    vf4* acc4 = (vf4*)acc;
#pragma unroll
    for (int i = 0; i < 4; i++) acc4[tid + i * 1024] = (vf4)0.f;   // 4096 float4
    __syncthreads();

    const int b = blockIdx.x;
    const int s = start[b];
    const int e = start[b + 1];
    const int lane = tid & 63;
    const int wid = tid >> 6;             // 0..15 waves

    const long long* pk = (const long long*)packed;

    // Each wave owns disjoint 64-edge chunks: [base, base+64).
    for (int base = s + wid * 64; base < e; base += 16 * 64) {
        int idx = base + lane;
        long long pv = 0;                 // pad: val=0 -> contributes 0 to row 0
        if (idx < e) pv = __builtin_nontemporal_load(&pk[idx]);
        int px = (int)pv;                 // (lrow<<19) | col
        int py = (int)(pv >> 32);         // val bits

        // 2-stage software pipeline, BATCH=8 edges per stage.
        float xv[BATCH];
        float vv[BATCH];
        int   lr[BATCH];

#pragma unroll
        for (int j = 0; j < BATCH; j++) {
            int sx = __builtin_amdgcn_readlane(px, j);
            int sy = __builtin_amdgcn_readlane(py, j);
            vv[j] = __int_as_float(sy);
            lr[j] = (int)(((unsigned)sx) >> 19);
            xv[j] = x[((size_t)(sx & 0x7FFFF) << 6) + lane];   // 256B/wave
        }
#pragma unroll
        for (int B = 1; B < 64 / BATCH; B++) {
            float xv2[BATCH];
            float vv2[BATCH];
            int   lr2[BATCH];
#pragma unroll
            for (int j = 0; j < BATCH; j++) {
                int sx = __builtin_amdgcn_readlane(px, B * BATCH + j);
                int sy = __builtin_amdgcn_readlane(py, B * BATCH + j);
                vv2[j] = __int_as_float(sy);
                lr2[j] = (int)(((unsigned)sx) >> 19);
                xv2[j] = x[((size_t)(sx & 0x7FFFF) << 6) + lane];
            }
            // drain previous batch while next batch's loads are in flight
#pragma unroll
            for (int j = 0; j < BATCH; j++)
                lds_fadd(&acc[(lr[j] << 6) + lane], vv[j] * xv[j]);
#pragma unroll
            for (int j = 0; j < BATCH; j++) {
                xv[j] = xv2[j]; vv[j] = vv2[j]; lr[j] = lr2[j];
            }
        }
#pragma unroll
        for (int j = 0; j < BATCH; j++)
            lds_fadd(&acc[(lr[j] << 6) + lane], vv[j] * xv[j]);
    }
    __syncthreads();

    // write out: rows [b*RPB, b*RPB+256), contiguous & coalesced
    const long long rbase = (long long)b * RPB;
    const vf4* accv = (const vf4*)acc;
    vf4* out4 = (vf4*)out;
#pragma unroll
    for (int i = 0; i < 4; i++) {
        int idx = tid + i * 1024;          // 0..4095 (row*16 + f4)
        int r = idx >> 4;
        if (rbase + r < n_nodes)
            __builtin_nontemporal_store(accv[idx], &out4[rbase * 16 + idx]);
    }
}

// ---------------- fallback (round-1 atomic version) ----------------
__global__ __launch_bounds__(256)
void graphconv_scatter(const float* __restrict__ x, const float* __restrict__ edge_vals,
                       const int* __restrict__ row, const int* __restrict__ col,
                       float* __restrict__ out, int n_edges) {
    int tid = blockIdx.x * blockDim.x + threadIdx.x;
    int lane16 = tid & 15;
    int e = tid >> 4;
    if (e >= n_edges) return;
    int r = row[e];
    int c = col[e];
    float v = edge_vals[e];
    const float4* xs = (const float4*)(x + (size_t)c * D_FEAT);
    float4 xv = xs[lane16];
    float* o = out + (size_t)r * D_FEAT + lane16 * 4;
    atomicAdd(o + 0, v * xv.x);
    atomicAdd(o + 1, v * xv.y);
    atomicAdd(o + 2, v * xv.z);
    atomicAdd(o + 3, v * xv.w);
}

extern "C" void kernel_launch(void* const* d_in, const int* in_sizes, int n_in,
                              void* d_out, int out_size, void* d_ws, size_t ws_size,
                              hipStream_t stream) {
    const float* x         = (const float*)d_in[0];
    const float* edge_vals = (const float*)d_in[1];
    const int*   row       = (const int*)d_in[2];
    const int*   col       = (const int*)d_in[3];
    float* out = (float*)d_out;

    const int n_nodes = in_sizes[0] / D_FEAT;
    const int n_edges = in_sizes[1];
    const int kb = (n_nodes + RPB - 1) >> BKT_SHIFT;

    // ---- workspace layout ----
    size_t off = 0;
    auto alloc = [&](size_t bytes) {
        size_t p = off;
        off += (bytes + 255) & ~size_t(255);
        return p;
    };
    size_t o_start    = alloc((size_t)(kb + 1) * sizeof(int));
    size_t o_gcursor  = alloc((size_t)kb * sizeof(int));
    size_t o_cnt      = alloc((size_t)kb * sizeof(int));
    size_t o_packed   = alloc((size_t)n_edges * sizeof(int2));

    if (kb > MAX_BKT || n_nodes > (1 << 19) || off > ws_size) {
        hipMemsetAsync(d_out, 0, (size_t)out_size * sizeof(float), stream);
        long long total_threads = (long long)n_edges * 16;
        int grid = (int)((total_threads + 255) / 256);
        graphconv_scatter<<<grid, 256, 0, stream>>>(x, edge_vals, row, col, out, n_edges);
        return;
    }

    char* wsb = (char*)d_ws;
    int*  start     = (int*)(wsb + o_start);
    int*  gcursor   = (int*)(wsb + o_gcursor);
    int*  cnt_g     = (int*)(wsb + o_cnt);
    int2* packed    = (int2*)(wsb + o_packed);

    const int nblksH = (n_edges + TILE_EDGES - 1) / TILE_EDGES;
    const int nblksB = (n_edges + TILE_BIN - 1) / TILE_BIN;

    hipMemsetAsync(cnt_g, 0, (size_t)kb * sizeof(int), stream);
    hist_kernel<<<nblksH, 256, 0, stream>>>(row, cnt_g, n_edges, kb);
    scan_kernel<<<1, 256, 0, stream>>>(cnt_g, start, gcursor, kb);
    bin_kernel<<<nblksB, BIN_THREADS, 0, stream>>>(row, col, edge_vals, gcursor,
                                                   packed, n_edges, kb);
    reduce_bucket<<<kb, 1024, 0, stream>>>(x, packed, start, out, n_nodes);
}

// Round 4
// 722.421 us; speedup vs baseline: 4.2893x; 4.2893x over previous
//
#include <hip/hip_runtime.h>

// GraphConv SpMM: out[row[e], :] += edge_vals[e] * x[col[e], :]
// N = 500000, E = 8000000, D = 64, fp32.
//
// Round 8 = Round 7 + compile fix (nontemporal load of int2 via long long).
//
// Pipeline (fused sort+reduce, no sorted writeback):
//   1. bucket histogram (bucket = row>>8, 1954 buckets)
//   2. single-block scan -> bucket run starts
//   3. bin edges into bucket runs (1024-thread blocks, packs
//      (lrow<<19 | col, val)). Order within bucket arbitrary.
//   4. sort_reduce: one 1024-thread block per bucket.
//      a) stage run (<=6144 edges) into LDS ed[] (48 KB, NT loads)
//      b) per-row histogram (LDS atomics) + 256-wide scan
//      c) build inverse permutation inv[pos]=edge_idx (ushort, 12 KB)
//      d) register-accumulate reduce: 64 groups x 16 lanes; each group
//         walks its row segment: inv[] (2B broadcast) -> ed[] (8B
//         broadcast) -> coalesced 256B float4 x-gather, 4-deep unroll,
//         NO atomics in the gather loop (rounds 5/6 lesson: LDS atomics
//         kill MLP; reg-accumulate measured 3.8 TB/s in round 4).
//      e) NT store out rows straight from registers.
//      Total LDS 63 KB -> 2 blocks/CU, 32 waves/CU.
//      Overflow (n > CAP): scan-filter the run from global per row group.

#define D_FEAT 64
#define RPB 256                // rows per bucket
#define BKT_SHIFT 8
#define MAX_BKT 2048
#define TILE_EDGES 8192        // hist tile (256 threads * EPT)
#define EPT 32                 // edges per thread in hist/bin
#define TILE_BIN 32768         // bin tile (1024 threads * EPT)
#define BIN_THREADS 1024
#define CAP 6144               // max staged edges per bucket

typedef float vf4 __attribute__((ext_vector_type(4)));

// ---------------- bucket histogram ----------------
__global__ __launch_bounds__(256)
void hist_kernel(const int* __restrict__ row, int* __restrict__ cnt_g,
                 int n_edges, int kb) {
    __shared__ int cnt[MAX_BKT];
    for (int i = threadIdx.x; i < kb; i += 256) cnt[i] = 0;
    __syncthreads();
    int base = blockIdx.x * TILE_EDGES;
#pragma unroll
    for (int k = 0; k < EPT; k++) {
        int e = base + k * 256 + threadIdx.x;
        if (e < n_edges) atomicAdd(&cnt[row[e] >> BKT_SHIFT], 1);
    }
    __syncthreads();
    for (int i = threadIdx.x; i < kb; i += 256) {
        int c = cnt[i];
        if (c) atomicAdd(&cnt_g[i], c);
    }
}

// ---------------- single-block scan over kb buckets ----------------
__global__ __launch_bounds__(256)
void scan_kernel(const int* __restrict__ cnt_g, int* __restrict__ start,
                 int* __restrict__ gcursor, int kb) {
    __shared__ int sums[256];
    int vals[8];
    int base = threadIdx.x * 8;
    int s = 0;
#pragma unroll
    for (int i = 0; i < 8; i++) {
        int idx = base + i;
        int v = (idx < kb) ? cnt_g[idx] : 0;
        s += v;
        vals[i] = s;
    }
    sums[threadIdx.x] = s;
    __syncthreads();
    for (int off = 1; off < 256; off <<= 1) {
        int t = (threadIdx.x >= off) ? sums[threadIdx.x - off] : 0;
        __syncthreads();
        sums[threadIdx.x] += t;
        __syncthreads();
    }
    int toff = (threadIdx.x > 0) ? sums[threadIdx.x - 1] : 0;
#pragma unroll
    for (int i = 0; i < 8; i++) {
        int idx = base + i;
        if (idx < kb) {
            int incl = vals[i] + toff;
            int v = vals[i] - (i ? vals[i - 1] : 0);
            start[idx + 1] = incl;
            gcursor[idx] = incl - v;
        }
    }
    if (threadIdx.x == 0) start[0] = 0;
}

// ---------------- bin edges into bucket runs ----------------
__global__ __launch_bounds__(BIN_THREADS)
void bin_kernel(const int* __restrict__ row, const int* __restrict__ col,
                const float* __restrict__ val,
                int* __restrict__ gcursor, int2* __restrict__ packed,
                int n_edges, int kb) {
    __shared__ int cnt[MAX_BKT];
    __shared__ int base_s[MAX_BKT];
    for (int i = threadIdx.x; i < kb; i += BIN_THREADS) cnt[i] = 0;
    __syncthreads();
    int tbase = blockIdx.x * TILE_BIN;
    int r_[EPT];
#pragma unroll
    for (int k = 0; k < EPT; k++) {
        int e = tbase + k * BIN_THREADS + threadIdx.x;
        int r = (e < n_edges) ? row[e] : -1;
        r_[k] = r;
        if (r >= 0) atomicAdd(&cnt[r >> BKT_SHIFT], 1);
    }
    __syncthreads();
    for (int i = threadIdx.x; i < kb; i += BIN_THREADS) {
        int c = cnt[i];
        base_s[i] = c ? atomicAdd(&gcursor[i], c) : 0;
        cnt[i] = 0;
    }
    __syncthreads();
#pragma unroll
    for (int k = 0; k < EPT; k++) {
        int r = r_[k];
        if (r >= 0) {
            int e = tbase + k * BIN_THREADS + threadIdx.x;
            int b = r >> BKT_SHIFT;
            int rank = atomicAdd(&cnt[b], 1);
            packed[base_s[b] + rank] =
                make_int2(((r & (RPB - 1)) << 19) | col[e], __float_as_int(val[e]));
        }
    }
}

// ---------------- fused per-bucket sort + reduce ----------------
__global__ __launch_bounds__(1024)
void sort_reduce(const float* __restrict__ x, const int2* __restrict__ packed,
                 const int* __restrict__ start, float* __restrict__ out,
                 int n_nodes) {
    __shared__ int2 ed[CAP];               // 48 KB: staged (unsorted) edges
    __shared__ unsigned short inv[CAP];    // 12 KB: sorted pos -> edge idx
    __shared__ int cnt[RPB];               // per-row count
    __shared__ int sc[RPB];                // inclusive scan
    __shared__ int cur[RPB];               // scatter cursor

    const int tid = threadIdx.x;
    const int b = blockIdx.x;
    const int s = start[b];
    const int e = start[b + 1];
    const int n = e - s;

    const int g = tid >> 4;                // 0..63 (16-lane row group)
    const int l16 = tid & 15;
    const vf4* x4 = (const vf4*)x;
    vf4* out4 = (vf4*)out;
    const long long rbase = (long long)b * RPB;

    if (n <= CAP) {
        if (tid < RPB) cnt[tid] = 0;
        __syncthreads();

        // a) stage + per-row histogram (NT load as long long, unpack)
        const long long* pk = (const long long*)packed;
        for (int i = tid; i < n; i += 1024) {
            long long pv = __builtin_nontemporal_load(&pk[s + i]);
            int2 r;
            r.x = (int)pv;
            r.y = (int)(pv >> 32);
            ed[i] = r;
            atomicAdd(&cnt[((unsigned)r.x) >> 19], 1);
        }
        __syncthreads();

        // b) inclusive scan over 256 row counts (all-thread barriers)
        if (tid < RPB) sc[tid] = cnt[tid];
        __syncthreads();
        for (int off = 1; off < RPB; off <<= 1) {
            int t = 0;
            if (tid < RPB && tid >= off) t = sc[tid - off];
            __syncthreads();
            if (tid < RPB) sc[tid] += t;
            __syncthreads();
        }
        if (tid < RPB) cur[tid] = (tid > 0) ? sc[tid - 1] : 0;
        __syncthreads();

        // c) inverse permutation (sorted pos -> staged idx)
        for (int i = tid; i < n; i += 1024) {
            int lr = ((unsigned)ed[i].x) >> 19;
            int d = atomicAdd(&cur[lr], 1);
            inv[d] = (unsigned short)i;
        }
        __syncthreads();

        // d) register-accumulate reduce: 4 passes x 64 rows
#pragma unroll
        for (int p = 0; p < 4; p++) {
            int r = p * 64 + g;
            int rs = r ? sc[r - 1] : 0;
            int re = sc[r];
            vf4 a = (vf4)0.f;
            int j = rs;
            for (; j + 3 < re; j += 4) {
                int i0 = inv[j], i1 = inv[j + 1], i2 = inv[j + 2], i3 = inv[j + 3];
                int2 e0 = ed[i0], e1 = ed[i1], e2 = ed[i2], e3 = ed[i3];
                vf4 x0 = x4[(size_t)(e0.x & 0x7FFFF) * 16 + l16];
                vf4 x1 = x4[(size_t)(e1.x & 0x7FFFF) * 16 + l16];
                vf4 x2 = x4[(size_t)(e2.x & 0x7FFFF) * 16 + l16];
                vf4 x3 = x4[(size_t)(e3.x & 0x7FFFF) * 16 + l16];
                a += __int_as_float(e0.y) * x0;
                a += __int_as_float(e1.y) * x1;
                a += __int_as_float(e2.y) * x2;
                a += __int_as_float(e3.y) * x3;
            }
            for (; j < re; j++) {
                int i0 = inv[j];
                int2 e0 = ed[i0];
                vf4 x0 = x4[(size_t)(e0.x & 0x7FFFF) * 16 + l16];
                a += __int_as_float(e0.y) * x0;
            }
            long long rg = rbase + r;
            if (rg < n_nodes)
                __builtin_nontemporal_store(a, &out4[rg * 16 + l16]);
        }
    } else {
        // overflow: scan-filter the run from global (rare correctness path)
#pragma unroll
        for (int p = 0; p < 4; p++) {
            int r = p * 64 + g;
            vf4 a = (vf4)0.f;
            for (int i = s; i < e; i++) {
                int2 e0 = packed[i];
                if ((int)(((unsigned)e0.x) >> 19) == r) {
                    vf4 x0 = x4[(size_t)(e0.x & 0x7FFFF) * 16 + l16];
                    a += __int_as_float(e0.y) * x0;
                }
            }
            long long rg = rbase + r;
            if (rg < n_nodes)
                __builtin_nontemporal_store(a, &out4[rg * 16 + l16]);
        }
    }
}

// ---------------- fallback (round-1 atomic version) ----------------
__global__ __launch_bounds__(256)
void graphconv_scatter(const float* __restrict__ x, const float* __restrict__ edge_vals,
                       const int* __restrict__ row, const int* __restrict__ col,
                       float* __restrict__ out, int n_edges) {
    int tid = blockIdx.x * blockDim.x + threadIdx.x;
    int lane16 = tid & 15;
    int e = tid >> 4;
    if (e >= n_edges) return;
    int r = row[e];
    int c = col[e];
    float v = edge_vals[e];
    const float4* xs = (const float4*)(x + (size_t)c * D_FEAT);
    float4 xv = xs[lane16];
    float* o = out + (size_t)r * D_FEAT + lane16 * 4;
    atomicAdd(o + 0, v * xv.x);
    atomicAdd(o + 1, v * xv.y);
    atomicAdd(o + 2, v * xv.z);
    atomicAdd(o + 3, v * xv.w);
}

extern "C" void kernel_launch(void* const* d_in, const int* in_sizes, int n_in,
                              void* d_out, int out_size, void* d_ws, size_t ws_size,
                              hipStream_t stream) {
    const float* x         = (const float*)d_in[0];
    const float* edge_vals = (const float*)d_in[1];
    const int*   row       = (const int*)d_in[2];
    const int*   col       = (const int*)d_in[3];
    float* out = (float*)d_out;

    const int n_nodes = in_sizes[0] / D_FEAT;
    const int n_edges = in_sizes[1];
    const int kb = (n_nodes + RPB - 1) >> BKT_SHIFT;

    // ---- workspace layout ----
    size_t off = 0;
    auto alloc = [&](size_t bytes) {
        size_t p = off;
        off += (bytes + 255) & ~size_t(255);
        return p;
    };
    size_t o_start    = alloc((size_t)(kb + 1) * sizeof(int));
    size_t o_gcursor  = alloc((size_t)kb * sizeof(int));
    size_t o_cnt      = alloc((size_t)kb * sizeof(int));
    size_t o_packed   = alloc((size_t)n_edges * sizeof(int2));

    if (kb > MAX_BKT || n_nodes > (1 << 19) || off > ws_size) {
        hipMemsetAsync(d_out, 0, (size_t)out_size * sizeof(float), stream);
        long long total_threads = (long long)n_edges * 16;
        int grid = (int)((total_threads + 255) / 256);
        graphconv_scatter<<<grid, 256, 0, stream>>>(x, edge_vals, row, col, out, n_edges);
        return;
    }

    char* wsb = (char*)d_ws;
    int*  start     = (int*)(wsb + o_start);
    int*  gcursor   = (int*)(wsb + o_gcursor);
    int*  cnt_g     = (int*)(wsb + o_cnt);
    int2* packed    = (int2*)(wsb + o_packed);

    const int nblksH = (n_edges + TILE_EDGES - 1) / TILE_EDGES;
    const int nblksB = (n_edges + TILE_BIN - 1) / TILE_BIN;

    hipMemsetAsync(cnt_g, 0, (size_t)kb * sizeof(int), stream);
    hist_kernel<<<nblksH, 256, 0, stream>>>(row, cnt_g, n_edges, kb);
    scan_kernel<<<1, 256, 0, stream>>>(cnt_g, start, gcursor, kb);
    bin_kernel<<<nblksB, BIN_THREADS, 0, stream>>>(row, col, edge_vals, gcursor,
                                                   packed, n_edges, kb);
    sort_reduce<<<kb, 1024, 0, stream>>>(x, packed, start, out, n_nodes);
}

// Round 5
// 657.471 us; speedup vs baseline: 4.7130x; 1.0988x over previous
//
#include <hip/hip_runtime.h>

// GraphConv SpMM: out[row[e], :] += edge_vals[e] * x[col[e], :]
// N = 500000, E = 8000000, D = 64, fp32.
//
// Round 9: medium buckets (1024 rows) to fix bin write-thrash.
//   1. hist: bucket = row>>10 (489 buckets), 1024-thr blocks
//      -> global-atomic chains 977 -> 245, counters 1954 -> 489.
//   2. single-block scan -> bucket run starts
//   3. bin: 1024-thr blocks, no register cache (row re-read is L2-hot),
//      per-block segments now 32768/489 = 67 edges = 536 B (>= 4 full
//      128B lines) -> write-allocate thrash eliminated (round-8 theory:
//      134B segments x ~64 co-resident blocks/XCD >> 4MB L2 -> partial-
//      line evictions ~2GB effective traffic).
//      packs (lrow10<<19 | col, val), 10+19 bits.
//   4. sort_reduce: 4 sub-blocks per medium bucket (blockIdx>>2, &3).
//      Stream parent run, wave-ballot filter own 256-row slice
//      ((px>>27)&3 == sb) into ed[] (48 KB), per-row hist/scan/inv,
//      then round-8's proven register-accumulate reduce (16 lanes/row,
//      4-deep unroll, no atomics in gather loop). Overflow (>CAP):
//      global scan-filter per row group.

#define D_FEAT 64
#define RPM 1024               // rows per medium bucket
#define RPB 256                // rows per sub-bucket (acc tile)
#define BKT_SHIFT 10
#define MAX_BKT 512
#define TILE 32768             // hist/bin tile (1024 threads * EPT)
#define EPT 32
#define NTHR 1024
#define CAP 6144               // max staged edges per sub-bucket

typedef float vf4 __attribute__((ext_vector_type(4)));

// ---------------- bucket histogram ----------------
__global__ __launch_bounds__(NTHR)
void hist_kernel(const int* __restrict__ row, int* __restrict__ cnt_g,
                 int n_edges, int kb) {
    __shared__ int cnt[MAX_BKT];
    for (int i = threadIdx.x; i < kb; i += NTHR) cnt[i] = 0;
    __syncthreads();
    int base = blockIdx.x * TILE;
#pragma unroll
    for (int k = 0; k < EPT; k++) {
        int e = base + k * NTHR + threadIdx.x;
        if (e < n_edges) atomicAdd(&cnt[row[e] >> BKT_SHIFT], 1);
    }
    __syncthreads();
    for (int i = threadIdx.x; i < kb; i += NTHR) {
        int c = cnt[i];
        if (c) atomicAdd(&cnt_g[i], c);
    }
}

// ---------------- single-block scan over kb buckets ----------------
__global__ __launch_bounds__(256)
void scan_kernel(const int* __restrict__ cnt_g, int* __restrict__ start,
                 int* __restrict__ gcursor, int kb) {
    __shared__ int sums[256];
    int vals[8];
    int base = threadIdx.x * 8;
    int s = 0;
#pragma unroll
    for (int i = 0; i < 8; i++) {
        int idx = base + i;
        int v = (idx < kb) ? cnt_g[idx] : 0;
        s += v;
        vals[i] = s;
    }
    sums[threadIdx.x] = s;
    __syncthreads();
    for (int off = 1; off < 256; off <<= 1) {
        int t = (threadIdx.x >= off) ? sums[threadIdx.x - off] : 0;
        __syncthreads();
        sums[threadIdx.x] += t;
        __syncthreads();
    }
    int toff = (threadIdx.x > 0) ? sums[threadIdx.x - 1] : 0;
#pragma unroll
    for (int i = 0; i < 8; i++) {
        int idx = base + i;
        if (idx < kb) {
            int incl = vals[i] + toff;
            int v = vals[i] - (i ? vals[i - 1] : 0);
            start[idx + 1] = incl;
            gcursor[idx] = incl - v;
        }
    }
    if (threadIdx.x == 0) start[0] = 0;
}

// ---------------- bin edges into bucket runs ----------------
__global__ __launch_bounds__(NTHR)
void bin_kernel(const int* __restrict__ row, const int* __restrict__ col,
                const float* __restrict__ val,
                int* __restrict__ gcursor, int2* __restrict__ packed,
                int n_edges, int kb) {
    __shared__ int cnt[MAX_BKT];
    __shared__ int base_s[MAX_BKT];
    for (int i = threadIdx.x; i < kb; i += NTHR) cnt[i] = 0;
    __syncthreads();
    int tbase = blockIdx.x * TILE;
#pragma unroll
    for (int k = 0; k < EPT; k++) {
        int e = tbase + k * NTHR + threadIdx.x;
        if (e < n_edges) atomicAdd(&cnt[row[e] >> BKT_SHIFT], 1);
    }
    __syncthreads();
    for (int i = threadIdx.x; i < kb; i += NTHR) {
        int c = cnt[i];
        base_s[i] = c ? atomicAdd(&gcursor[i], c) : 0;
        cnt[i] = 0;
    }
    __syncthreads();
#pragma unroll
    for (int k = 0; k < EPT; k++) {
        int e = tbase + k * NTHR + threadIdx.x;
        if (e < n_edges) {
            int r = row[e];               // L2-hot re-read (no reg cache)
            int b = r >> BKT_SHIFT;
            int rank = atomicAdd(&cnt[b], 1);
            packed[base_s[b] + rank] =
                make_int2(((r & (RPM - 1)) << 19) | col[e], __float_as_int(val[e]));
        }
    }
}

// ---------------- fused per-sub-bucket filter + sort + reduce ----------------
__global__ __launch_bounds__(NTHR)
void sort_reduce(const float* __restrict__ x, const int2* __restrict__ packed,
                 const int* __restrict__ start, float* __restrict__ out,
                 int n_nodes) {
    __shared__ int2 ed[CAP];               // 48 KB: staged filtered edges
    __shared__ unsigned short inv[CAP];    // 12 KB: sorted pos -> staged idx
    __shared__ int cnt[RPB];
    __shared__ int sc[RPB];
    __shared__ int cur[RPB];
    __shared__ int ns_sh;

    const int tid = threadIdx.x;
    const int bm = blockIdx.x >> 2;        // medium bucket
    const int sb = blockIdx.x & 3;         // 256-row sub-bucket
    const int s = start[bm];
    const int e = start[bm + 1];
    const int lane = tid & 63;

    const int g = tid >> 4;                // 0..63 (16-lane row group)
    const int l16 = tid & 15;
    const vf4* x4 = (const vf4*)x;
    vf4* out4 = (vf4*)out;
    const long long rbase = (long long)bm * RPM + (long long)sb * RPB;

    if (tid == 0) ns_sh = 0;
    if (tid < RPB) cnt[tid] = 0;
    __syncthreads();

    // a) stream run, wave-ballot filter own slice into ed[] + row hist
    const long long* pk = (const long long*)packed;
    for (int ib = s; ib < e; ib += NTHR) {
        int i = ib + tid;
        bool m = false;
        int px = 0, py = 0;
        if (i < e) {
            long long pv = __builtin_nontemporal_load(&pk[i]);
            px = (int)pv;
            py = (int)(pv >> 32);
            m = (((px >> 27) & 3) == sb);
        }
        unsigned long long mk = __ballot(m);
        if (mk) {
            int leader = __builtin_ctzll(mk);
            int base = 0;
            if (lane == leader) base = atomicAdd(&ns_sh, __popcll(mk));
            base = __shfl(base, leader);
            if (m) {
                int d = base + __popcll(mk & ((1ull << lane) - 1));
                if (d < CAP) ed[d] = make_int2(px, py);
                atomicAdd(&cnt[(px >> 19) & 255], 1);
            }
        }
    }
    __syncthreads();
    const int nf = ns_sh;

    if (nf <= CAP) {
        // b) inclusive scan over 256 row counts
        if (tid < RPB) sc[tid] = cnt[tid];
        __syncthreads();
        for (int off = 1; off < RPB; off <<= 1) {
            int t = 0;
            if (tid < RPB && tid >= off) t = sc[tid - off];
            __syncthreads();
            if (tid < RPB) sc[tid] += t;
            __syncthreads();
        }
        if (tid < RPB) cur[tid] = (tid > 0) ? sc[tid - 1] : 0;
        __syncthreads();

        // c) inverse permutation (sorted pos -> staged idx)
        for (int i = tid; i < nf; i += NTHR) {
            int lr = (ed[i].x >> 19) & 255;
            int d = atomicAdd(&cur[lr], 1);
            inv[d] = (unsigned short)i;
        }
        __syncthreads();

        // d) register-accumulate reduce: 4 passes x 64 rows
#pragma unroll
        for (int p = 0; p < 4; p++) {
            int r = p * 64 + g;
            int rs = r ? sc[r - 1] : 0;
            int re = sc[r];
            vf4 a = (vf4)0.f;
            int j = rs;
            for (; j + 3 < re; j += 4) {
                int i0 = inv[j], i1 = inv[j + 1], i2 = inv[j + 2], i3 = inv[j + 3];
                int2 e0 = ed[i0], e1 = ed[i1], e2 = ed[i2], e3 = ed[i3];
                vf4 x0 = x4[(size_t)(e0.x & 0x7FFFF) * 16 + l16];
                vf4 x1 = x4[(size_t)(e1.x & 0x7FFFF) * 16 + l16];
                vf4 x2 = x4[(size_t)(e2.x & 0x7FFFF) * 16 + l16];
                vf4 x3 = x4[(size_t)(e3.x & 0x7FFFF) * 16 + l16];
                a += __int_as_float(e0.y) * x0;
                a += __int_as_float(e1.y) * x1;
                a += __int_as_float(e2.y) * x2;
                a += __int_as_float(e3.y) * x3;
            }
            for (; j < re; j++) {
                int i0 = inv[j];
                int2 e0 = ed[i0];
                vf4 x0 = x4[(size_t)(e0.x & 0x7FFFF) * 16 + l16];
                a += __int_as_float(e0.y) * x0;
            }
            long long rg = rbase + r;
            if (rg < n_nodes)
                __builtin_nontemporal_store(a, &out4[rg * 16 + l16]);
        }
    } else {
        // overflow: scan-filter the run from global (rare correctness path)
#pragma unroll
        for (int p = 0; p < 4; p++) {
            int r = p * 64 + g;
            int lt = (sb << 8) | r;        // target lrow10
            vf4 a = (vf4)0.f;
            for (int i = s; i < e; i++) {
                int2 e0 = packed[i];
                if (((e0.x >> 19) & 1023) == lt) {
                    vf4 x0 = x4[(size_t)(e0.x & 0x7FFFF) * 16 + l16];
                    a += __int_as_float(e0.y) * x0;
                }
            }
            long long rg = rbase + r;
            if (rg < n_nodes)
                __builtin_nontemporal_store(a, &out4[rg * 16 + l16]);
        }
    }
}

// ---------------- fallback (round-1 atomic version) ----------------
__global__ __launch_bounds__(256)
void graphconv_scatter(const float* __restrict__ x, const float* __restrict__ edge_vals,
                       const int* __restrict__ row, const int* __restrict__ col,
                       float* __restrict__ out, int n_edges) {
    int tid = blockIdx.x * blockDim.x + threadIdx.x;
    int lane16 = tid & 15;
    int e = tid >> 4;
    if (e >= n_edges) return;
    int r = row[e];
    int c = col[e];
    float v = edge_vals[e];
    const float4* xs = (const float4*)(x + (size_t)c * D_FEAT);
    float4 xv = xs[lane16];
    float* o = out + (size_t)r * D_FEAT + lane16 * 4;
    atomicAdd(o + 0, v * xv.x);
    atomicAdd(o + 1, v * xv.y);
    atomicAdd(o + 2, v * xv.z);
    atomicAdd(o + 3, v * xv.w);
}

extern "C" void kernel_launch(void* const* d_in, const int* in_sizes, int n_in,
                              void* d_out, int out_size, void* d_ws, size_t ws_size,
                              hipStream_t stream) {
    const float* x         = (const float*)d_in[0];
    const float* edge_vals = (const float*)d_in[1];
    const int*   row       = (const int*)d_in[2];
    const int*   col       = (const int*)d_in[3];
    float* out = (float*)d_out;

    const int n_nodes = in_sizes[0] / D_FEAT;
    const int n_edges = in_sizes[1];
    const int kb = (n_nodes + RPM - 1) >> BKT_SHIFT;

    // ---- workspace layout ----
    size_t off = 0;
    auto alloc = [&](size_t bytes) {
        size_t p = off;
        off += (bytes + 255) & ~size_t(255);
        return p;
    };
    size_t o_start    = alloc((size_t)(kb + 1) * sizeof(int));
    size_t o_gcursor  = alloc((size_t)kb * sizeof(int));
    size_t o_cnt      = alloc((size_t)kb * sizeof(int));
    size_t o_packed   = alloc((size_t)n_edges * sizeof(int2));

    if (kb > MAX_BKT || n_nodes > (1 << 19) || off > ws_size) {
        hipMemsetAsync(d_out, 0, (size_t)out_size * sizeof(float), stream);
        long long total_threads = (long long)n_edges * 16;
        int grid = (int)((total_threads + 255) / 256);
        graphconv_scatter<<<grid, 256, 0, stream>>>(x, edge_vals, row, col, out, n_edges);
        return;
    }

    char* wsb = (char*)d_ws;
    int*  start     = (int*)(wsb + o_start);
    int*  gcursor   = (int*)(wsb + o_gcursor);
    int*  cnt_g     = (int*)(wsb + o_cnt);
    int2* packed    = (int2*)(wsb + o_packed);

    const int nblks = (n_edges + TILE - 1) / TILE;

    hipMemsetAsync(cnt_g, 0, (size_t)kb * sizeof(int), stream);
    hist_kernel<<<nblks, NTHR, 0, stream>>>(row, cnt_g, n_edges, kb);
    scan_kernel<<<1, 256, 0, stream>>>(cnt_g, start, gcursor, kb);
    bin_kernel<<<nblks, NTHR, 0, stream>>>(row, col, edge_vals, gcursor,
                                           packed, n_edges, kb);
    sort_reduce<<<kb * 4, NTHR, 0, stream>>>(x, packed, start, out, n_nodes);
}